// Round 1
// baseline (127.436 us; speedup 1.0000x reference)
//
#include <hip/hip_runtime.h>

// PatchwiseHadamard collapses algebraically:
//   out = alpha * x  everywhere, where alpha = dot(out_w, conv_w)
//   plus 256*beta at each 256x256 patch's (0,0) corner,
//   where beta = dot(out_w, conv_b) + out_b.
// Proof: H_norm (Sylvester) is orthogonal AND symmetric, so
// H(HxH^T)H^T = x; the bias term beta*J transforms to 256*beta at (0,0).
//
// This revision: the op is a pure 134 MB stream (read 64 MiB + write 64 MiB,
// floor ~21.3 us at 6.3 TB/s achievable). Changes vs previous version:
//  - grid capped at 2048 blocks (8/CU), each thread handles 8 float4s at
//    stride gridDim*blockDim: full per-instruction coalescing, 8 independent
//    loads in flight per thread (vmcnt-ordered -> store k waits only load k).
//    n4 = 4,194,304 = 2048*256*8 exactly, so no tail.
//  - non-temporal loads/stores (zero-reuse stream; harness poison fill
//    flushes LLC each iteration anyway).
//  - alpha/beta prologue now runs 2048x not 16384x.

typedef float f4 __attribute__((ext_vector_type(4)));

constexpr int BLK = 256;
constexpr int NBLK = 2048;      // 8 blocks/CU on 256 CUs
constexpr int PER_THREAD = 8;   // 2048*256*8 == 4,194,304 == n4 exactly

// x layout: (B=4, 1, H=2048, W=2048) flat. For float4 index i, element
// base = 4*i: w = base & 2047, h = (base >> 11) & 2047 (B stride 2^22).
// Corner iff (w & 255) == 0 && (h & 255) == 0  <=>  (base & 0x7F8FF) == 0.
// Corners are 16B-aligned so only element .x of a float4 can be a corner.
__global__ __launch_bounds__(BLK) void scale_corner(
        const f4* __restrict__ x, f4* __restrict__ out,
        const float* __restrict__ conv_w, const float* __restrict__ conv_b,
        const float* __restrict__ out_w, const float* __restrict__ out_b,
        int n4) {
    __shared__ float s_ab[2];
    if (threadIdx.x == 0) {
        float alpha = 0.f, beta = 0.f;
#pragma unroll
        for (int c = 0; c < 16; ++c) {
            alpha = fmaf(conv_w[c], out_w[c], alpha);
            beta  = fmaf(conv_b[c], out_w[c], beta);
        }
        s_ab[0] = alpha;
        s_ab[1] = 256.0f * (beta + out_b[0]);
    }
    __syncthreads();
    const float alpha = s_ab[0];
    const float cbias = s_ab[1];

    const int stride = NBLK * BLK;                  // 524,288 float4s
    const int i = blockIdx.x * BLK + threadIdx.x;

    if (i + (PER_THREAD - 1) * stride < n4) {
        // Fast path (taken by every thread at the bench shape): 8 batched
        // independent nt loads, then scale+store in load-completion order.
        f4 v[PER_THREAD];
#pragma unroll
        for (int k = 0; k < PER_THREAD; ++k)
            v[k] = __builtin_nontemporal_load(&x[i + k * stride]);
#pragma unroll
        for (int k = 0; k < PER_THREAD; ++k) {
            const int idx = i + k * stride;
            f4 r = v[k] * alpha;
            const int base = idx << 2;
            if ((base & 0x7F8FF) == 0) r.x += cbias;
            __builtin_nontemporal_store(r, &out[idx]);
        }
    } else {
        // Generic fallback (not taken at the bench shape).
        for (int idx = i; idx < n4; idx += stride) {
            f4 r = __builtin_nontemporal_load(&x[idx]) * alpha;
            const int base = idx << 2;
            if ((base & 0x7F8FF) == 0) r.x += cbias;
            __builtin_nontemporal_store(r, &out[idx]);
        }
    }
}

extern "C" void kernel_launch(void* const* d_in, const int* in_sizes, int n_in,
                              void* d_out, int out_size, void* d_ws, size_t ws_size,
                              hipStream_t stream) {
    const float* x      = (const float*)d_in[0];
    const float* conv_w = (const float*)d_in[1];
    const float* conv_b = (const float*)d_in[2];
    const float* out_w  = (const float*)d_in[3];
    const float* out_b  = (const float*)d_in[4];
    float* out = (float*)d_out;

    int n4 = out_size / 4;   // 16,777,216 / 4 = 4,194,304 float4s
    scale_corner<<<NBLK, BLK, 0, stream>>>(
        (const f4*)x, (f4*)out, conv_w, conv_b, out_w, out_b, n4);
}

// Round 2
// 117.317 us; speedup vs baseline: 1.0863x; 1.0863x over previous
//
#include <hip/hip_runtime.h>

// PatchwiseHadamard collapses algebraically:
//   out = alpha * x  everywhere, where alpha = dot(out_w, conv_w)
//   plus 256*beta at each 256x256 patch's (0,0) corner,
//   where beta = dot(out_w, conv_b) + out_b.
// Proof: H_norm (Sylvester) is orthogonal AND symmetric, so
// H(HxH^T)H^T = x; the bias term beta*J transforms to 256*beta at (0,0).
//
// Single fused kernel: thread 0 of each block computes alpha/beta from the
// 33 parameter floats (L2-broadcast, ~2 MB total traffic vs 134 MB stream),
// removing the serialized prologue kernel + d_ws round-trip from the graph.
//
// R2 note: controlled revert to the R0 artifact (best harness-verified,
// 115.7/117.9 us). R1's batched 8x/thread + nontemporal variant benched
// +9.5 us, but the harness fills in that run were also 1-7% slower
// (environmental load). This revert disambiguates kernel-real vs noise.

// x layout: (B=4, 1, H=2048, W=2048) flat. For float4 index i, element
// base = 4*i: w = base & 2047, h = (base >> 11) & 2047 (B stride 2^22).
// Corner iff (w & 255) == 0 && (h & 255) == 0; corners are 16B-aligned so
// only lane-element .x can be a corner.
__global__ __launch_bounds__(256) void scale_corner(
        const float4* __restrict__ x, float4* __restrict__ out,
        const float* __restrict__ conv_w, const float* __restrict__ conv_b,
        const float* __restrict__ out_w, const float* __restrict__ out_b,
        int n4) {
    __shared__ float s_ab[2];
    if (threadIdx.x == 0) {
        float alpha = 0.f, beta = 0.f;
#pragma unroll
        for (int c = 0; c < 16; ++c) {
            alpha = fmaf(conv_w[c], out_w[c], alpha);
            beta  = fmaf(conv_b[c], out_w[c], beta);
        }
        s_ab[0] = alpha;
        s_ab[1] = 256.0f * (beta + out_b[0]);
    }
    __syncthreads();

    int i = blockIdx.x * blockDim.x + threadIdx.x;
    if (i >= n4) return;
    float alpha = s_ab[0];
    float4 v = x[i];
    v.x *= alpha;
    v.y *= alpha;
    v.z *= alpha;
    v.w *= alpha;
    int base = i << 2;
    if (((base & 255) | ((base >> 11) & 255)) == 0) {
        v.x += s_ab[1];
    }
    out[i] = v;
}

extern "C" void kernel_launch(void* const* d_in, const int* in_sizes, int n_in,
                              void* d_out, int out_size, void* d_ws, size_t ws_size,
                              hipStream_t stream) {
    const float* x      = (const float*)d_in[0];
    const float* conv_w = (const float*)d_in[1];
    const float* conv_b = (const float*)d_in[2];
    const float* out_w  = (const float*)d_in[3];
    const float* out_b  = (const float*)d_in[4];
    float* out = (float*)d_out;

    int n4 = out_size / 4;               // 16,777,216 / 4 = 4,194,304 float4s
    int blocks = (n4 + 255) / 256;       // 16,384 blocks
    scale_corner<<<blocks, 256, 0, stream>>>(
        (const float4*)x, (float4*)out, conv_w, conv_b, out_w, out_b, n4);
}